// Round 1
// baseline (19999.400 us; speedup 1.0000x reference)
//
#include <hip/hip_runtime.h>
#include <math.h>

#define NUM_BASIS 8
#define SQRT3 1.7320508075688772f
#define SQRT2 1.4142135623730951f
#define INV_SQRT_DEG 0.17677669529663687f   // 1/sqrt(32)
#define PI_F 3.14159265358979323846f

__device__ __forceinline__ float sigmoidf_(float x) { return 1.0f / (1.0f + __expf(-x)); }
__device__ __forceinline__ float siluf_(float x) { return x * sigmoidf_(x); }

// ---------------------------------------------------------------------------
// Per-edge geometry + radial embedding (computed once, reused by all layers)
// ---------------------------------------------------------------------------
__global__ __launch_bounds__(256) void edge_pre(
    const float* __restrict__ pos, const int* __restrict__ src,
    const int* __restrict__ dst, const float* __restrict__ cs,
    const float* __restrict__ cell, const int* __restrict__ img,
    float* __restrict__ emb, float* __restrict__ y1x,
    float* __restrict__ y1y, float* __restrict__ y1z, int E)
{
    int e = blockIdx.x * blockDim.x + threadIdx.x;
    if (e >= E) return;
    int si = src[e], di = dst[e];
    float vx = pos[di*3+0] - pos[si*3+0];
    float vy = pos[di*3+1] - pos[si*3+1];
    float vz = pos[di*3+2] - pos[si*3+2];
    float c0 = cs[e*3+0], c1 = cs[e*3+1], c2 = cs[e*3+2];
    const float* M = cell + (size_t)img[si] * 9;
    vx += c0*M[0] + c1*M[3] + c2*M[6];
    vy += c0*M[1] + c1*M[4] + c2*M[7];
    vz += c0*M[2] + c1*M[5] + c2*M[8];
    float r  = sqrtf(vx*vx + vy*vy + vz*vz);
    float rs = fmaxf(r, 1e-9f);
    float inv = 1.0f / rs;
    y1x[e] = SQRT3 * vx * inv;
    y1y[e] = SQRT3 * vy * inv;
    y1z[e] = SQRT3 * vz * inv;
    // polynomial cutoff (p=6): 1 - 28 x^6 + 48 x^7 - 21 x^8, zero for x>=1
    float x = r * (1.0f / 5.0f);
    float x2 = x*x, x6 = x2*x2*x2;
    float fc = 1.0f - 28.0f*x6 + 48.0f*x6*x - 21.0f*x6*x2;
    if (x >= 1.0f) fc = 0.0f;
    float pre = sqrtf(2.0f / 5.0f) * inv * fc;
    float t = PI_F * rs * (1.0f / 5.0f);
    #pragma unroll
    for (int n = 1; n <= NUM_BASIS; n++)
        emb[(size_t)e*NUM_BASIS + (n-1)] = pre * __sinf((float)n * t);
}

// ---------------------------------------------------------------------------
// s[n] = w_lin_in[atom_type[n]]  (one-hot @ W)
// ---------------------------------------------------------------------------
__global__ __launch_bounds__(256) void node_init(
    const int* __restrict__ type, const float* __restrict__ wlin,
    float* __restrict__ s, int N)
{
    int i = blockIdx.x * blockDim.x + threadIdx.x;
    if (i >= N * 16) return;
    int n = i >> 4, q = i & 15;
    float4 val = *(const float4*)(wlin + (size_t)type[n]*64 + q*4);
    *(float4*)(s + (size_t)n*64 + q*4) = val;
}

// ---------------------------------------------------------------------------
// The big one: per-edge radial MLP + tensor-product messages + atomic scatter
// Thread per edge. Weights read with wave-uniform indices -> scalar loads.
// ---------------------------------------------------------------------------
__global__ __launch_bounds__(256) void edge_msg(
    const float* __restrict__ emb, const float* __restrict__ y1x,
    const float* __restrict__ y1y, const float* __restrict__ y1z,
    const int* __restrict__ src, const int* __restrict__ dst,
    const float* __restrict__ s, const float* __restrict__ vx,
    const float* __restrict__ vy, const float* __restrict__ vz,
    const float* __restrict__ W1, const float* __restrict__ B1,
    const float* __restrict__ W2,
    float* __restrict__ aggs, float* __restrict__ aggvx,
    float* __restrict__ aggvy, float* __restrict__ aggvz, int E)
{
    int e = blockIdx.x * blockDim.x + threadIdx.x;
    if (e >= E) return;
    int si = src[e], di = dst[e];

    float emb8[8];
    {
        float4 a = *(const float4*)(emb + (size_t)e*8);
        float4 b = *(const float4*)(emb + (size_t)e*8 + 4);
        emb8[0]=a.x; emb8[1]=a.y; emb8[2]=a.z; emb8[3]=a.w;
        emb8[4]=b.x; emb8[5]=b.y; emb8[6]=b.z; emb8[7]=b.w;
    }

    // hidden layer: h = silu(emb @ W1 + b1), W1 is (8,64) row-major
    float h[64];
    #pragma unroll
    for (int k = 0; k < 64; k++) h[k] = B1[k];
    #pragma unroll
    for (int j = 0; j < 8; j++) {
        float ej = emb8[j];
        #pragma unroll
        for (int k = 0; k < 64; k++)
            h[k] = fmaf(ej, W1[j*64 + k], h[k]);
    }
    #pragma unroll
    for (int k = 0; k < 64; k++) h[k] = siluf_(h[k]);

    float yx = y1x[e], yy = y1y[e], yz = y1z[e];
    const float* sb  = s  + (size_t)si*64;
    const float* vxb = vx + (size_t)si*64;
    const float* vyb = vy + (size_t)si*64;
    const float* vzb = vz + (size_t)si*64;
    float* as_d  = aggs  + (size_t)di*64;
    float* avx_d = aggvx + (size_t)di*64;
    float* avy_d = aggvy + (size_t)di*64;
    float* avz_d = aggvz + (size_t)di*64;

    // channel chunks of 4; W2 is (64,320) row-major, paths at +0,+64,...,+256
    #pragma unroll 1
    for (int c0 = 0; c0 < 64; c0 += 4) {
        float w1a[4] = {0,0,0,0}, w2a[4] = {0,0,0,0}, w3a[4] = {0,0,0,0};
        float w4a[4] = {0,0,0,0}, w5a[4] = {0,0,0,0};
        #pragma unroll
        for (int k = 0; k < 64; k++) {
            float hk = h[k];
            const float* W2k = W2 + k*320 + c0;
            #pragma unroll
            for (int i = 0; i < 4; i++) {
                w1a[i] = fmaf(hk, W2k[      i], w1a[i]);
                w2a[i] = fmaf(hk, W2k[ 64 + i], w2a[i]);
                w3a[i] = fmaf(hk, W2k[128 + i], w3a[i]);
                w4a[i] = fmaf(hk, W2k[192 + i], w4a[i]);
                w5a[i] = fmaf(hk, W2k[256 + i], w5a[i]);
            }
        }
        float4 s4  = *(const float4*)(sb  + c0);
        float4 x4  = *(const float4*)(vxb + c0);
        float4 y4  = *(const float4*)(vyb + c0);
        float4 z4  = *(const float4*)(vzb + c0);
        float sv[4]  = {s4.x, s4.y, s4.z, s4.w};
        float vxs[4] = {x4.x, x4.y, x4.z, x4.w};
        float vys[4] = {y4.x, y4.y, y4.z, y4.w};
        float vzs[4] = {z4.x, z4.y, z4.z, z4.w};
        #pragma unroll
        for (int i = 0; i < 4; i++) {
            float vdoty = vxs[i]*yx + vys[i]*yy + vzs[i]*yz;
            float ms = w1a[i]*sv[i] + w2a[i]*vdoty*(1.0f/SQRT3);
            float cxv = vys[i]*yz - vzs[i]*yy;
            float cyv = vzs[i]*yx - vxs[i]*yz;
            float czv = vxs[i]*yy - vys[i]*yx;
            float mvx = w3a[i]*sv[i]*yx + w4a[i]*vxs[i] + w5a[i]*cxv*(1.0f/SQRT2);
            float mvy = w3a[i]*sv[i]*yy + w4a[i]*vys[i] + w5a[i]*cyv*(1.0f/SQRT2);
            float mvz = w3a[i]*sv[i]*yz + w4a[i]*vzs[i] + w5a[i]*czv*(1.0f/SQRT2);
            atomicAdd(as_d  + c0 + i, ms);
            atomicAdd(avx_d + c0 + i, mvx);
            atomicAdd(avy_d + c0 + i, mvy);
            atomicAdd(avz_d + c0 + i, mvz);
        }
    }
}

// ---------------------------------------------------------------------------
// Gated self-interaction + resnet. One wave per node, lane = output channel.
// ---------------------------------------------------------------------------
__global__ __launch_bounds__(256) void node_update(
    float* __restrict__ s, float* __restrict__ vx,
    float* __restrict__ vy, float* __restrict__ vz,
    const float* __restrict__ aggs, const float* __restrict__ aggvx,
    const float* __restrict__ aggvy, const float* __restrict__ aggvz,
    const float* __restrict__ Wg, const float* __restrict__ Ws,
    const float* __restrict__ Wv, int N)
{
    int wid  = (blockIdx.x * blockDim.x + threadIdx.x) >> 6;
    int lane = threadIdx.x & 63;
    if (wid >= N) return;
    size_t base = (size_t)wid * 64;
    float a0 = aggs [base + lane] * INV_SQRT_DEG;
    float ax = aggvx[base + lane] * INV_SQRT_DEG;
    float ay = aggvy[base + lane] * INV_SQRT_DEG;
    float az = aggvz[base + lane] * INV_SQRT_DEG;
    float g = 0.f, ss = 0.f, ox = 0.f, oy = 0.f, oz = 0.f;
    #pragma unroll 4
    for (int c = 0; c < 64; c++) {
        float a  = __shfl(a0, c);
        float bx = __shfl(ax, c);
        float by = __shfl(ay, c);
        float bz = __shfl(az, c);
        float wg = Wg[c*64 + lane];
        float ws = Ws[c*64 + lane];
        float wv = Wv[c*64 + lane];
        g  = fmaf(a,  wg, g);
        ss = fmaf(a,  ws, ss);
        ox = fmaf(bx, wv, ox);
        oy = fmaf(by, wv, oy);
        oz = fmaf(bz, wv, oz);
    }
    float gate = sigmoidf_(g);
    s [base + lane] += siluf_(ss);
    vx[base + lane] += ox * gate;
    vy[base + lane] += oy * gate;
    vz[base + lane] += oz * gate;
}

// ---------------------------------------------------------------------------
// atomic_energy = (s @ w_lin1) @ w_lin2
// ---------------------------------------------------------------------------
__global__ __launch_bounds__(256) void energy_out(
    const float* __restrict__ s, const float* __restrict__ Wl1,
    const float* __restrict__ Wl2, float* __restrict__ out, int N)
{
    int n = blockIdx.x * blockDim.x + threadIdx.x;
    if (n >= N) return;
    float acc[16];
    #pragma unroll
    for (int j = 0; j < 16; j++) acc[j] = 0.f;
    #pragma unroll 1
    for (int c = 0; c < 64; c++) {
        float sc = s[(size_t)n*64 + c];
        #pragma unroll
        for (int j = 0; j < 16; j++)
            acc[j] = fmaf(sc, Wl1[c*16 + j], acc[j]);
    }
    float e = 0.f;
    #pragma unroll
    for (int j = 0; j < 16; j++) e = fmaf(acc[j], Wl2[j], e);
    out[n] = e;
}

extern "C" void kernel_launch(void* const* d_in, const int* in_sizes, int n_in,
                              void* d_out, int out_size, void* d_ws, size_t ws_size,
                              hipStream_t stream)
{
    const int*   atom_type = (const int*)  d_in[0];
    const float* pos       = (const float*)d_in[1];
    const int*   src       = (const int*)  d_in[2];
    const int*   dst       = (const int*)  d_in[3];
    const float* cs        = (const float*)d_in[4];
    const float* cell      = (const float*)d_in[5];
    const int*   img       = (const int*)  d_in[6];
    const float* wlin_in   = (const float*)d_in[7];
    const float* mw1       = (const float*)d_in[8];
    const float* mb1       = (const float*)d_in[9];
    const float* mw2       = (const float*)d_in[10];
    const float* wss       = (const float*)d_in[11];
    const float* wsv       = (const float*)d_in[12];
    const float* wg        = (const float*)d_in[13];
    const float* wl1       = (const float*)d_in[14];
    const float* wl2       = (const float*)d_in[15];
    int N = in_sizes[0];
    int E = in_sizes[2];

    float* ws = (float*)d_ws;
    size_t off = 0;
    float* emb  = ws + off; off += (size_t)E * 8;
    float* y1x  = ws + off; off += E;
    float* y1y  = ws + off; off += E;
    float* y1z  = ws + off; off += E;
    float* s    = ws + off; off += (size_t)N * 64;
    float* vx   = ws + off; off += (size_t)N * 64;   // vx,vy,vz contiguous
    float* vy   = ws + off; off += (size_t)N * 64;
    float* vz   = ws + off; off += (size_t)N * 64;
    float* aggs = ws + off; off += (size_t)N * 64;   // aggs..aggvz contiguous
    float* aggvx= ws + off; off += (size_t)N * 64;
    float* aggvy= ws + off; off += (size_t)N * 64;
    float* aggvz= ws + off; off += (size_t)N * 64;

    // zero v (poisoned with 0xAA before every timed call)
    hipMemsetAsync(vx, 0, (size_t)N * 64 * 3 * sizeof(float), stream);

    edge_pre<<<(E + 255) / 256, 256, 0, stream>>>(
        pos, src, dst, cs, cell, img, emb, y1x, y1y, y1z, E);
    node_init<<<(N * 16 + 255) / 256, 256, 0, stream>>>(atom_type, wlin_in, s, N);

    for (int L = 0; L < 3; L++) {
        hipMemsetAsync(aggs, 0, (size_t)N * 64 * 4 * sizeof(float), stream);
        edge_msg<<<(E + 255) / 256, 256, 0, stream>>>(
            emb, y1x, y1y, y1z, src, dst, s, vx, vy, vz,
            mw1 + L*8*64, mb1 + L*64, mw2 + (size_t)L*64*320,
            aggs, aggvx, aggvy, aggvz, E);
        node_update<<<(N * 64 + 255) / 256, 256, 0, stream>>>(
            s, vx, vy, vz, aggs, aggvx, aggvy, aggvz,
            wg + L*4096, wss + L*4096, wsv + L*4096, N);
    }

    energy_out<<<(N + 255) / 256, 256, 0, stream>>>(s, wl1, wl2, (float*)d_out, N);
}

// Round 3
// 2615.278 us; speedup vs baseline: 7.6471x; 7.6471x over previous
//
#include <hip/hip_runtime.h>
#include <math.h>

#define NUM_BASIS 8
#define SQRT3 1.7320508075688772f
#define SQRT2 1.4142135623730951f
#define INV_SQRT_DEG 0.17677669529663687f   // 1/sqrt(32)
#define PI_F 3.14159265358979323846f

__device__ __forceinline__ float sigmoidf_(float x) { return 1.0f / (1.0f + __expf(-x)); }
__device__ __forceinline__ float siluf_(float x) { return x * sigmoidf_(x); }

// ---------------------------------------------------------------------------
// CSR build: degree count -> single-block scan -> fused geometry+scatter
// ---------------------------------------------------------------------------
__global__ __launch_bounds__(256) void count_deg(
    const int* __restrict__ dst, int* __restrict__ deg, int E)
{
    int e = blockIdx.x * blockDim.x + threadIdx.x;
    if (e < E) atomicAdd(&deg[dst[e]], 1);
}

__global__ __launch_bounds__(1024) void scan_deg(
    const int* __restrict__ deg, int* __restrict__ cursor, int N)
{
    __shared__ int buf[1024];
    __shared__ int carry_s;
    int tid = threadIdx.x;
    if (tid == 0) carry_s = 0;
    __syncthreads();
    for (int base = 0; base < N; base += 1024) {
        int i = base + tid;
        int v = (i < N) ? deg[i] : 0;
        buf[tid] = v;
        __syncthreads();
        for (int off = 1; off < 1024; off <<= 1) {
            int t = (tid >= off) ? buf[tid - off] : 0;
            __syncthreads();
            buf[tid] += t;
            __syncthreads();
        }
        int incl = buf[tid];
        int carry = carry_s;
        if (i < N) cursor[i] = carry + incl - v;   // exclusive prefix
        __syncthreads();
        if (tid == 1023) carry_s = carry + incl;
        __syncthreads();
    }
}

// Per-edge geometry + radial embedding, scattered directly into CSR slots.
__global__ __launch_bounds__(256) void edge_pre_scatter(
    const float* __restrict__ pos, const int* __restrict__ src,
    const int* __restrict__ dst, const float* __restrict__ cs,
    const float* __restrict__ cell, const int* __restrict__ img,
    int* __restrict__ cursor, float* __restrict__ emb,
    float4* __restrict__ y14, int* __restrict__ srcp,
    int* __restrict__ dstp, int E)
{
    int e = blockIdx.x * blockDim.x + threadIdx.x;
    if (e >= E) return;
    int si = src[e], di = dst[e];
    int slot = atomicAdd(&cursor[di], 1);
    srcp[slot] = si;
    dstp[slot] = di;
    float vx = pos[di*3+0] - pos[si*3+0];
    float vy = pos[di*3+1] - pos[si*3+1];
    float vz = pos[di*3+2] - pos[si*3+2];
    float c0 = cs[(size_t)e*3+0], c1 = cs[(size_t)e*3+1], c2 = cs[(size_t)e*3+2];
    const float* M = cell + (size_t)img[si] * 9;
    vx += c0*M[0] + c1*M[3] + c2*M[6];
    vy += c0*M[1] + c1*M[4] + c2*M[7];
    vz += c0*M[2] + c1*M[5] + c2*M[8];
    float r  = sqrtf(vx*vx + vy*vy + vz*vz);
    float rs = fmaxf(r, 1e-9f);
    float inv = 1.0f / rs;
    y14[slot] = make_float4(SQRT3*vx*inv, SQRT3*vy*inv, SQRT3*vz*inv, 0.0f);
    // polynomial cutoff p=6: 1 - 28 x^6 + 48 x^7 - 21 x^8 (0 for x>=1)
    float x = r * (1.0f / 5.0f);
    float x2 = x*x, x6 = x2*x2*x2;
    float fc = 1.0f - 28.0f*x6 + 48.0f*x6*x - 21.0f*x6*x2;
    if (x >= 1.0f) fc = 0.0f;
    float pre = sqrtf(2.0f / 5.0f) * inv * fc;
    float t = PI_F * rs * (1.0f / 5.0f);
    #pragma unroll
    for (int n = 1; n <= NUM_BASIS; n++)
        emb[(size_t)slot*NUM_BASIS + (n-1)] = pre * __sinf((float)n * t);
}

// ---------------------------------------------------------------------------
// W2 (3,64,320) -> W2T[L][q][k][path][i], contiguous per channel-chunk q
// ---------------------------------------------------------------------------
__global__ __launch_bounds__(256) void transpose_w2(
    const float* __restrict__ W2, float* __restrict__ W2T)
{
    int idx = blockIdx.x * blockDim.x + threadIdx.x;
    if (idx >= 3 * 20480) return;
    int L = idx / 20480;
    int rem = idx % 20480;
    int q = rem / 1280;
    int r2 = rem % 1280;
    int k = r2 / 20;
    int pi = r2 % 20;
    int path = pi / 4, i = pi % 4;
    W2T[idx] = W2[L * 20480 + k * 320 + path * 64 + q * 4 + i];
}

// ---------------------------------------------------------------------------
// s[n] = w_lin_in[atom_type[n]]
// ---------------------------------------------------------------------------
__global__ __launch_bounds__(256) void node_init(
    const int* __restrict__ type, const float* __restrict__ wlin,
    float* __restrict__ s, int N)
{
    int i = blockIdx.x * blockDim.x + threadIdx.x;
    if (i >= N * 16) return;
    int n = i >> 4, q = i & 15;
    float4 val = *(const float4*)(wlin + (size_t)type[n]*64 + q*4);
    *(float4*)(s + (size_t)n*64 + q*4) = val;
}

// ---------------------------------------------------------------------------
// Per-edge radial MLP + tensor product; in-wave segmented reduction by dst
// (CSR-sorted => equal-dst lanes contiguous), only segment tails do atomics.
// ---------------------------------------------------------------------------
__global__ __launch_bounds__(256) void edge_msg(
    const float* __restrict__ emb, const float4* __restrict__ y14,
    const int* __restrict__ srcp, const int* __restrict__ dstp,
    const float* __restrict__ s, const float* __restrict__ vx,
    const float* __restrict__ vy, const float* __restrict__ vz,
    const float* __restrict__ W1, const float* __restrict__ B1,
    const float* __restrict__ W2T,
    float* __restrict__ aggs, float* __restrict__ aggvx,
    float* __restrict__ aggvy, float* __restrict__ aggvz, int E)
{
    int p = blockIdx.x * blockDim.x + threadIdx.x;
    int lane = threadIdx.x & 63;
    bool valid = p < E;
    int pc = valid ? p : (E - 1);
    int si = srcp[pc];
    int d  = valid ? dstp[pc] : -1;

    // segment structure for this wave (shared across all chunks)
    int d_next = __shfl_down(d, 1);
    bool is_tail = valid && ((lane == 63) || (d_next != d));
    bool take[6];
    #pragma unroll
    for (int sb = 0; sb < 6; sb++) {
        int off = 1 << sb;
        int d_prev = __shfl_up(d, off);
        take[sb] = (lane >= off) && (d_prev == d);
    }

    float emb8[8];
    {
        float4 a = *(const float4*)(emb + (size_t)pc*8);
        float4 b = *(const float4*)(emb + (size_t)pc*8 + 4);
        emb8[0]=a.x; emb8[1]=a.y; emb8[2]=a.z; emb8[3]=a.w;
        emb8[4]=b.x; emb8[5]=b.y; emb8[6]=b.z; emb8[7]=b.w;
    }

    // hidden layer: h = silu(emb @ W1 + b1); W1 (8,64) row-major, scalar loads
    float h[64];
    #pragma unroll
    for (int k = 0; k < 64; k++) h[k] = B1[k];
    #pragma unroll
    for (int j = 0; j < 8; j++) {
        float ej = emb8[j];
        #pragma unroll
        for (int k = 0; k < 64; k++)
            h[k] = fmaf(ej, W1[j*64 + k], h[k]);
    }
    #pragma unroll
    for (int k = 0; k < 64; k++) h[k] = siluf_(h[k]);

    float4 yv = y14[pc];
    float yx = yv.x, yy = yv.y, yz = yv.z;
    const float* sb_  = s  + (size_t)si*64;
    const float* vxb = vx + (size_t)si*64;
    const float* vyb = vy + (size_t)si*64;
    const float* vzb = vz + (size_t)si*64;

    #pragma unroll 1
    for (int c0 = 0; c0 < 64; c0 += 4) {
        const float* Wq = W2T + (c0/4) * 1280;
        float w1a[4] = {0,0,0,0}, w2a[4] = {0,0,0,0}, w3a[4] = {0,0,0,0};
        float w4a[4] = {0,0,0,0}, w5a[4] = {0,0,0,0};
        #pragma unroll
        for (int k = 0; k < 64; k++) {
            float hk = h[k];
            const float* wk = Wq + k*20;
            #pragma unroll
            for (int i = 0; i < 4; i++) {
                w1a[i] = fmaf(hk, wk[     i], w1a[i]);
                w2a[i] = fmaf(hk, wk[ 4 + i], w2a[i]);
                w3a[i] = fmaf(hk, wk[ 8 + i], w3a[i]);
                w4a[i] = fmaf(hk, wk[12 + i], w4a[i]);
                w5a[i] = fmaf(hk, wk[16 + i], w5a[i]);
            }
        }
        float4 s4  = *(const float4*)(sb_ + c0);
        float4 x4  = *(const float4*)(vxb + c0);
        float4 y4  = *(const float4*)(vyb + c0);
        float4 z4  = *(const float4*)(vzb + c0);
        float sv[4]  = {s4.x, s4.y, s4.z, s4.w};
        float vxs[4] = {x4.x, x4.y, x4.z, x4.w};
        float vys[4] = {y4.x, y4.y, y4.z, y4.w};
        float vzs[4] = {z4.x, z4.y, z4.z, z4.w};
        float ms[4], mx[4], my[4], mz[4];
        #pragma unroll
        for (int i = 0; i < 4; i++) {
            float vdoty = vxs[i]*yx + vys[i]*yy + vzs[i]*yz;
            ms[i] = w1a[i]*sv[i] + w2a[i]*vdoty*(1.0f/SQRT3);
            float cxv = vys[i]*yz - vzs[i]*yy;
            float cyv = vzs[i]*yx - vxs[i]*yz;
            float czv = vxs[i]*yy - vys[i]*yx;
            mx[i] = w3a[i]*sv[i]*yx + w4a[i]*vxs[i] + w5a[i]*cxv*(1.0f/SQRT2);
            my[i] = w3a[i]*sv[i]*yy + w4a[i]*vys[i] + w5a[i]*cyv*(1.0f/SQRT2);
            mz[i] = w3a[i]*sv[i]*yz + w4a[i]*vzs[i] + w5a[i]*czv*(1.0f/SQRT2);
        }
        // segmented inclusive scan by dst (sorted): tails hold segment sums
        #pragma unroll
        for (int sb2 = 0; sb2 < 6; sb2++) {
            int off = 1 << sb2;
            #pragma unroll
            for (int i = 0; i < 4; i++) {
                float t0 = __shfl_up(ms[i], off);
                float t1 = __shfl_up(mx[i], off);
                float t2 = __shfl_up(my[i], off);
                float t3 = __shfl_up(mz[i], off);
                if (take[sb2]) { ms[i]+=t0; mx[i]+=t1; my[i]+=t2; mz[i]+=t3; }
            }
        }
        if (is_tail) {
            #pragma unroll
            for (int i = 0; i < 4; i++) {
                atomicAdd(aggs  + (size_t)d*64 + c0 + i, ms[i]);
                atomicAdd(aggvx + (size_t)d*64 + c0 + i, mx[i]);
                atomicAdd(aggvy + (size_t)d*64 + c0 + i, my[i]);
                atomicAdd(aggvz + (size_t)d*64 + c0 + i, mz[i]);
            }
        }
    }
}

// ---------------------------------------------------------------------------
// Gated self-interaction + resnet. One wave per node, lane = channel.
// ---------------------------------------------------------------------------
__global__ __launch_bounds__(256) void node_update(
    float* __restrict__ s, float* __restrict__ vx,
    float* __restrict__ vy, float* __restrict__ vz,
    const float* __restrict__ aggs, const float* __restrict__ aggvx,
    const float* __restrict__ aggvy, const float* __restrict__ aggvz,
    const float* __restrict__ Wg, const float* __restrict__ Ws,
    const float* __restrict__ Wv, int N)
{
    int wid  = (blockIdx.x * blockDim.x + threadIdx.x) >> 6;
    int lane = threadIdx.x & 63;
    if (wid >= N) return;
    size_t base = (size_t)wid * 64;
    float a0 = aggs [base + lane] * INV_SQRT_DEG;
    float ax = aggvx[base + lane] * INV_SQRT_DEG;
    float ay = aggvy[base + lane] * INV_SQRT_DEG;
    float az = aggvz[base + lane] * INV_SQRT_DEG;
    float g = 0.f, ss = 0.f, ox = 0.f, oy = 0.f, oz = 0.f;
    #pragma unroll 4
    for (int c = 0; c < 64; c++) {
        float a  = __shfl(a0, c);
        float bx = __shfl(ax, c);
        float by = __shfl(ay, c);
        float bz = __shfl(az, c);
        float wg = Wg[c*64 + lane];
        float ws = Ws[c*64 + lane];
        float wv = Wv[c*64 + lane];
        g  = fmaf(a,  wg, g);
        ss = fmaf(a,  ws, ss);
        ox = fmaf(bx, wv, ox);
        oy = fmaf(by, wv, oy);
        oz = fmaf(bz, wv, oz);
    }
    float gate = sigmoidf_(g);
    s [base + lane] += siluf_(ss);
    vx[base + lane] += ox * gate;
    vy[base + lane] += oy * gate;
    vz[base + lane] += oz * gate;
}

// ---------------------------------------------------------------------------
// atomic_energy = (s @ w_lin1) @ w_lin2
// ---------------------------------------------------------------------------
__global__ __launch_bounds__(256) void energy_out(
    const float* __restrict__ s, const float* __restrict__ Wl1,
    const float* __restrict__ Wl2, float* __restrict__ out, int N)
{
    int n = blockIdx.x * blockDim.x + threadIdx.x;
    if (n >= N) return;
    float acc[16];
    #pragma unroll
    for (int j = 0; j < 16; j++) acc[j] = 0.f;
    #pragma unroll 1
    for (int c = 0; c < 64; c++) {
        float sc = s[(size_t)n*64 + c];
        #pragma unroll
        for (int j = 0; j < 16; j++)
            acc[j] = fmaf(sc, Wl1[c*16 + j], acc[j]);
    }
    float e = 0.f;
    #pragma unroll
    for (int j = 0; j < 16; j++) e = fmaf(acc[j], Wl2[j], e);
    out[n] = e;
}

extern "C" void kernel_launch(void* const* d_in, const int* in_sizes, int n_in,
                              void* d_out, int out_size, void* d_ws, size_t ws_size,
                              hipStream_t stream)
{
    const int*   atom_type = (const int*)  d_in[0];
    const float* pos       = (const float*)d_in[1];
    const int*   src       = (const int*)  d_in[2];
    const int*   dst       = (const int*)  d_in[3];
    const float* cs        = (const float*)d_in[4];
    const float* cell      = (const float*)d_in[5];
    const int*   img       = (const int*)  d_in[6];
    const float* wlin_in   = (const float*)d_in[7];
    const float* mw1       = (const float*)d_in[8];
    const float* mb1       = (const float*)d_in[9];
    const float* mw2       = (const float*)d_in[10];
    const float* wss       = (const float*)d_in[11];
    const float* wsv       = (const float*)d_in[12];
    const float* wg        = (const float*)d_in[13];
    const float* wl1       = (const float*)d_in[14];
    const float* wl2       = (const float*)d_in[15];
    int N = in_sizes[0];
    int E = in_sizes[2];

    char* w = (char*)d_ws;
    float*  emb  = (float*)w;  w += (size_t)E * 8 * sizeof(float);   // 16.4 MB
    float4* y14  = (float4*)w; w += (size_t)E * sizeof(float4);      //  8.2 MB
    int*    srcp = (int*)w;    w += (size_t)E * sizeof(int);         //  2.0 MB
    int*    dstp = (int*)w;    w += (size_t)E * sizeof(int);         //  2.0 MB
    float*  s    = (float*)w;  w += (size_t)N * 64 * sizeof(float);
    float*  vx   = (float*)w;  w += (size_t)N * 64 * sizeof(float);  // vx..vz contiguous
    float*  vy   = (float*)w;  w += (size_t)N * 64 * sizeof(float);
    float*  vz   = (float*)w;  w += (size_t)N * 64 * sizeof(float);
    float*  aggs = (float*)w;  w += (size_t)N * 64 * sizeof(float);  // aggs..aggvz contiguous
    float*  aggvx= (float*)w;  w += (size_t)N * 64 * sizeof(float);
    float*  aggvy= (float*)w;  w += (size_t)N * 64 * sizeof(float);
    float*  aggvz= (float*)w;  w += (size_t)N * 64 * sizeof(float);
    float*  w2t  = (float*)w;  w += (size_t)3 * 20480 * sizeof(float);
    int*    deg  = (int*)w;    w += (size_t)N * sizeof(int);
    int*    curs = (int*)w;    w += (size_t)N * sizeof(int);

    hipMemsetAsync(deg, 0, (size_t)N * sizeof(int), stream);
    hipMemsetAsync(vx, 0, (size_t)N * 64 * 3 * sizeof(float), stream);

    count_deg<<<(E + 255) / 256, 256, 0, stream>>>(dst, deg, E);
    scan_deg<<<1, 1024, 0, stream>>>(deg, curs, N);
    transpose_w2<<<(3 * 20480 + 255) / 256, 256, 0, stream>>>(mw2, w2t);
    edge_pre_scatter<<<(E + 255) / 256, 256, 0, stream>>>(
        pos, src, dst, cs, cell, img, curs, emb, y14, srcp, dstp, E);
    node_init<<<(N * 16 + 255) / 256, 256, 0, stream>>>(atom_type, wlin_in, s, N);

    for (int L = 0; L < 3; L++) {
        hipMemsetAsync(aggs, 0, (size_t)N * 64 * 4 * sizeof(float), stream);
        edge_msg<<<(E + 255) / 256, 256, 0, stream>>>(
            emb, y14, srcp, dstp, s, vx, vy, vz,
            mw1 + L * 8 * 64, mb1 + L * 64, w2t + (size_t)L * 20480,
            aggs, aggvx, aggvy, aggvz, E);
        node_update<<<(N * 64 + 255) / 256, 256, 0, stream>>>(
            s, vx, vy, vz, aggs, aggvx, aggvy, aggvz,
            wg + L * 4096, wss + L * 4096, wsv + L * 4096, N);
    }

    energy_out<<<(N + 255) / 256, 256, 0, stream>>>(s, wl1, wl2, (float*)d_out, N);
}